// Round 1
// baseline (326.218 us; speedup 1.0000x reference)
//
#include <hip/hip_runtime.h>

#define LROW 4096
#define TILE 1024
#define NT   256
#define GM1  0.4f

__device__ __forceinline__ float frcp(float x){ return __builtin_amdgcn_rcpf(x); }
__device__ __forceinline__ float frsq(float x){ return __builtin_amdgcn_rsqf(x); }

// Roe characteristic flux for one interface.
// s_m,q_m,sH_m: center point precomputes; s_o,...: other side; d0..d2: du.
// RIGHT=true  -> sign=-1 (lambda - |lambda| = 2*min(l,0))
// RIGHT=false -> sign=+1 (lambda + |lambda| = 2*max(l,0))
template<bool RIGHT>
__device__ __forceinline__ void flux_side(
    float s_m, float q_m, float sH_m,
    float s_o, float q_o, float sH_o,
    float d0, float d1, float d2,
    float& R0, float& R1, float& R2)
{
    float rS  = frcp(s_o + s_m);
    float ua  = (q_o + q_m) * rS;
    float Ha  = (sH_o + sH_m) * rS;
    float c2  = 0.5f * ua * ua;          // 0.5*u_a^2
    float ca2 = GM1 * (Ha - c2);
    float rca = frsq(ca2);
    float ca  = ca2 * rca;               // sqrt(ca2)
    float c1  = (0.5f * GM1) * (rca * rca); // 0.5*(g-1)/ca2
    float c3  = ca * (1.0f / GM1);
    float l1  = ua - ca, l3 = ua + ca;
    float w1  = RIGHT ? fminf(l1, 0.f) : fmaxf(l1, 0.f);
    float w2  = RIGHT ? fminf(ua, 0.f) : fmaxf(ua, 0.f);
    float w3  = RIGHT ? fminf(l3, 0.f) : fmaxf(l3, 0.f);
    float L0  = (2.f * c1) * w1 * ((c2 + ua * c3) * d0 - (ua + c3) * d1 + d2);
    float L1  = (4.f * c1) * w2 * ((ca * c3 - c2) * d0 + ua * d1 - d2);
    float L2  = (2.f * c1) * w3 * ((c2 - ua * c3) * d0 - (ua - c3) * d1 + d2);
    R0 = L0 + L1 + L2;
    R1 = l1 * L0 + ua * L1 + l3 * L2;
    float uc = ua * ca;
    R2 = (Ha - uc) * L0 + c2 * L1 + (Ha + uc) * L2;
}

// arrays: 0=rho 1=mo 2=E 3=s 4=q 5=sH
#define EW (NT + 1)

__global__ __launch_bounds__(NT, 4)
void roe_kernel(const float* __restrict__ u, float* __restrict__ out)
{
    // edge-exchange LDS: eR[a][i] = rightmost elem of thread i-1 (i>=1), [0]=left halo
    //                    eL[a][i] = leftmost  elem of thread i,    [NT]=right halo
    __shared__ float eR[6 * EW];
    __shared__ float eL[6 * EW];

    const int t    = threadIdx.x;
    const int base = blockIdx.x * TILE;
    const size_t rowoff = (size_t)blockIdx.y * (3 * LROW);
    const float* pr = u + rowoff;
    const float* pm = pr + LROW;
    const float* pE = pr + 2 * LROW;

    const int j0 = base + 4 * t;
    float4 r4 = *(const float4*)(pr + j0);
    float4 m4 = *(const float4*)(pm + j0);
    float4 E4 = *(const float4*)(pE + j0);

    float rv[4] = {r4.x, r4.y, r4.z, r4.w};
    float mv[4] = {m4.x, m4.y, m4.z, m4.w};
    float Ev[4] = {E4.x, E4.y, E4.z, E4.w};
    float sv[4], qv[4], sHv[4];
#pragma unroll
    for (int k = 0; k < 4; k++) {
        float rs   = frsq(rv[k]);
        float rinv = rs * rs;
        float p    = GM1 * (Ev[k] - 0.5f * mv[k] * mv[k] * rinv);
        float H    = (Ev[k] + p) * rinv;
        sv[k]  = rv[k] * rs;
        qv[k]  = mv[k] * rs;
        sHv[k] = sv[k] * H;
    }

    // publish edges (stride-1 across lanes -> conflict-free)
    eR[0 * EW + t + 1] = rv[3];  eL[0 * EW + t] = rv[0];
    eR[1 * EW + t + 1] = mv[3];  eL[1 * EW + t] = mv[0];
    eR[2 * EW + t + 1] = Ev[3];  eL[2 * EW + t] = Ev[0];
    eR[3 * EW + t + 1] = sv[3];  eL[3 * EW + t] = sv[0];
    eR[4 * EW + t + 1] = qv[3];  eL[4 * EW + t] = qv[0];
    eR[5 * EW + t + 1] = sHv[3]; eL[5 * EW + t] = sHv[0];

    if (t < 2) {
        // t==0: block-left halo (clamped) -> eR[a][0]
        // t==1: block-right halo (clamped) -> eL[a][NT]
        int j = (t == 0) ? (base > 0 ? base - 1 : 0)
                         : (base + TILE < LROW ? base + TILE : LROW - 1);
        float r = pr[j], m = pm[j], e = pE[j];
        float rs   = frsq(r);
        float rinv = rs * rs;
        float p    = GM1 * (e - 0.5f * m * m * rinv);
        float H    = (e + p) * rinv;
        float s    = r * rs;
        int h = (t == 0) ? 0 : NT;
        float* dst = (t == 0) ? eR : eL;
        dst[0 * EW + h] = r;
        dst[1 * EW + h] = m;
        dst[2 * EW + h] = e;
        dst[3 * EW + h] = s;
        dst[4 * EW + h] = m * rs;
        dst[5 * EW + h] = s * H;
    }
    __syncthreads();

    float rL = eR[0 * EW + t], mL = eR[1 * EW + t], EL = eR[2 * EW + t];
    float sL = eR[3 * EW + t], qL = eR[4 * EW + t], sHL = eR[5 * EW + t];
    float rR = eL[0 * EW + t + 1], mR = eL[1 * EW + t + 1], ER = eL[2 * EW + t + 1];
    float sR = eL[3 * EW + t + 1], qR = eL[4 * EW + t + 1], sHR = eL[5 * EW + t + 1];

    float o0[4], o1[4], o2[4];
#pragma unroll
    for (int k = 0; k < 4; k++) {
        float rl  = k ? rv[k - 1]  : rL;
        float ml  = k ? mv[k - 1]  : mL;
        float El_ = k ? Ev[k - 1]  : EL;
        float sl  = k ? sv[k - 1]  : sL;
        float ql  = k ? qv[k - 1]  : qL;
        float sHl = k ? sHv[k - 1] : sHL;
        float rr  = (k < 3) ? rv[k + 1]  : rR;
        float mr  = (k < 3) ? mv[k + 1]  : mR;
        float Er  = (k < 3) ? Ev[k + 1]  : ER;
        float sr  = (k < 3) ? sv[k + 1]  : sR;
        float qr  = (k < 3) ? qv[k + 1]  : qR;
        float sHr = (k < 3) ? sHv[k + 1] : sHR;

        float R0r, R1r, R2r, R0l, R1l, R2l;
        flux_side<true >(sv[k], qv[k], sHv[k], sr, qr, sHr,
                         rr - rv[k], mr - mv[k], Er - Ev[k], R0r, R1r, R2r);
        flux_side<false>(sv[k], qv[k], sHv[k], sl, ql, sHl,
                         rv[k] - rl, mv[k] - ml, Ev[k] - El_, R0l, R1l, R2l);
        const float SC = -100.0f; // -1/(2*DX)
        o0[k] = SC * (R0r + R0l);
        o1[k] = SC * (R1r + R1l);
        o2[k] = SC * (R2r + R2l);
    }

    float* qo = out + rowoff;
    *(float4*)(qo + j0)            = make_float4(o0[0], o0[1], o0[2], o0[3]);
    *(float4*)(qo + LROW + j0)     = make_float4(o1[0], o1[1], o1[2], o1[3]);
    *(float4*)(qo + 2 * LROW + j0) = make_float4(o2[0], o2[1], o2[2], o2[3]);
}

extern "C" void kernel_launch(void* const* d_in, const int* in_sizes, int n_in,
                              void* d_out, int out_size, void* d_ws, size_t ws_size,
                              hipStream_t stream)
{
    const float* u = (const float*)d_in[0];
    float* out = (float*)d_out;
    const int M = in_sizes[0] / (3 * LROW); // 4096 rows
    dim3 grid(LROW / TILE, M);
    roe_kernel<<<grid, NT, 0, stream>>>(u, out);
}

// Round 2
// 322.698 us; speedup vs baseline: 1.0109x; 1.0109x over previous
//
#include <hip/hip_runtime.h>

#define LROW 4096
#define NT   256
#define EPT  4            // elements per thread
#define TILE (NT * EPT)   // 1024
#define GM1  0.4f

__device__ __forceinline__ float frcp(float x){ return __builtin_amdgcn_rcpf(x); }
__device__ __forceinline__ float frsq(float x){ return __builtin_amdgcn_rsqf(x); }

// Roe characteristic flux for one interface.
// RIGHT=true  -> sign=-1: (l + sign*|l|)/2 = min(l,0)
// RIGHT=false -> sign=+1: (l + sign*|l|)/2 = max(l,0)
template<bool RIGHT>
__device__ __forceinline__ void flux_side(
    float s_m, float q_m, float sH_m,
    float s_o, float q_o, float sH_o,
    float d0, float d1, float d2,
    float& R0, float& R1, float& R2)
{
    float rS  = frcp(s_o + s_m);
    float ua  = (q_o + q_m) * rS;
    float Ha  = (sH_o + sH_m) * rS;
    float c2  = 0.5f * ua * ua;              // 0.5*u_a^2
    float ca2 = GM1 * (Ha - c2);
    float rca = frsq(ca2);
    float ca  = ca2 * rca;                   // sqrt(ca2)
    float c1  = (0.5f * GM1) * (rca * rca);  // 0.5*(g-1)/ca2
    float c3  = ca * (1.0f / GM1);
    float l1  = ua - ca, l3 = ua + ca;
    float w1  = RIGHT ? fminf(l1, 0.f) : fmaxf(l1, 0.f);
    float w2  = RIGHT ? fminf(ua, 0.f) : fmaxf(ua, 0.f);
    float w3  = RIGHT ? fminf(l3, 0.f) : fmaxf(l3, 0.f);
    float L0  = (2.f * c1) * w1 * ((c2 + ua * c3) * d0 - (ua + c3) * d1 + d2);
    float L1  = (4.f * c1) * w2 * ((ca * c3 - c2) * d0 + ua * d1 - d2);
    float L2  = (2.f * c1) * w3 * ((c2 - ua * c3) * d0 - (ua - c3) * d1 + d2);
    R0 = L0 + L1 + L2;
    R1 = l1 * L0 + ua * L1 + l3 * L2;
    float uc = ua * ca;
    R2 = (Ha - uc) * L0 + c2 * L1 + (Ha + uc) * L2;
}

// Register-only stencil: each thread owns 4 points + loads its own 2 clamped
// halo scalars (L1-resident -> near-free). No LDS, no __syncthreads, no
// divergent halo path, no VGPR cap (no min-waves launch bound).
__global__ __launch_bounds__(NT)
void roe_kernel(const float* __restrict__ u, float* __restrict__ out)
{
    const int t    = threadIdx.x;
    const int base = blockIdx.x * TILE;
    const size_t rowoff = (size_t)blockIdx.y * (3 * LROW);
    const float* pr = u + rowoff;
    const float* pm = pr + LROW;
    const float* pE = pr + 2 * LROW;

    const int j0 = base + EPT * t;
    int jm = (j0 == 0) ? 0 : j0 - 1;
    int jp = (j0 + EPT >= LROW) ? (LROW - 1) : j0 + EPT;

    float4 r4 = *(const float4*)(pr + j0);
    float4 m4 = *(const float4*)(pm + j0);
    float4 E4 = *(const float4*)(pE + j0);

    // points -1..4 (6 total): index 0 = left halo, 5 = right halo
    float rv[6] = {pr[jm], r4.x, r4.y, r4.z, r4.w, pr[jp]};
    float mv[6] = {pm[jm], m4.x, m4.y, m4.z, m4.w, pm[jp]};
    float Ev[6] = {pE[jm], E4.x, E4.y, E4.z, E4.w, pE[jp]};

    float sv[6], qv[6], sHv[6];
#pragma unroll
    for (int k = 0; k < 6; k++) {
        float rs   = frsq(rv[k]);
        float rinv = rs * rs;
        float p    = GM1 * (Ev[k] - 0.5f * mv[k] * mv[k] * rinv);
        float H    = (Ev[k] + p) * rinv;
        sv[k]  = rv[k] * rs;       // sqrt(rho)
        qv[k]  = mv[k] * rs;       // m / sqrt(rho)
        sHv[k] = sv[k] * H;        // sqrt(rho) * H
    }

    float o0[4], o1[4], o2[4];
#pragma unroll
    for (int k = 0; k < 4; k++) {
        const int c = k + 1, l = k, r = k + 2;
        float R0r, R1r, R2r, R0l, R1l, R2l;
        flux_side<true >(sv[c], qv[c], sHv[c], sv[r], qv[r], sHv[r],
                         rv[r] - rv[c], mv[r] - mv[c], Ev[r] - Ev[c],
                         R0r, R1r, R2r);
        flux_side<false>(sv[c], qv[c], sHv[c], sv[l], qv[l], sHv[l],
                         rv[c] - rv[l], mv[c] - mv[l], Ev[c] - Ev[l],
                         R0l, R1l, R2l);
        const float SC = -100.0f;  // -1/(2*DX)
        o0[k] = SC * (R0r + R0l);
        o1[k] = SC * (R1r + R1l);
        o2[k] = SC * (R2r + R2l);
    }

    float* qo = out + rowoff;
    *(float4*)(qo + j0)            = make_float4(o0[0], o0[1], o0[2], o0[3]);
    *(float4*)(qo + LROW + j0)     = make_float4(o1[0], o1[1], o1[2], o1[3]);
    *(float4*)(qo + 2 * LROW + j0) = make_float4(o2[0], o2[1], o2[2], o2[3]);
}

extern "C" void kernel_launch(void* const* d_in, const int* in_sizes, int n_in,
                              void* d_out, int out_size, void* d_ws, size_t ws_size,
                              hipStream_t stream)
{
    const float* u = (const float*)d_in[0];
    float* out = (float*)d_out;
    const int M = in_sizes[0] / (3 * LROW); // 4096 rows
    dim3 grid(LROW / TILE, M);
    roe_kernel<<<grid, NT, 0, stream>>>(u, out);
}